// Round 14
// baseline (538.979 us; speedup 1.0000x reference)
//
#include <hip/hip_runtime.h>

typedef unsigned short ushort_t;
typedef __attribute__((ext_vector_type(8))) short s8v;
typedef __attribute__((ext_vector_type(4))) float f4v;

__device__ __forceinline__ float b2f(ushort_t h) {
    union { unsigned u; float f; } c; c.u = ((unsigned)h) << 16; return c.f;
}
__device__ __forceinline__ ushort_t f2b(float f) {
    union { float f; unsigned u; } c; c.f = f;
    unsigned u = c.u;
    return (ushort_t)((u + 0x7fffu + ((u >> 16) & 1u)) >> 16);
}

__device__ __forceinline__ void glds16(const void* g, void* l) {
    __builtin_amdgcn_global_load_lds(
        (const __attribute__((address_space(1))) void*)g,
        (__attribute__((address_space(3))) void*)l, 16, 0, 0);
}

// ---------------- weight transpose f32 [K,N] -> bf16 [N,K] ----------------
template <int PERM>
__global__ __launch_bounds__(256) void trans_k(const float* __restrict__ W,
                                               ushort_t* __restrict__ Wt,
                                               int K, int N) {
    __shared__ float tile[64][65];
    int k0 = blockIdx.x * 64, n0 = blockIdx.y * 64;
    int t = threadIdx.x;
    int c = t & 63, r4 = t >> 6;
#pragma unroll
    for (int i = 0; i < 16; ++i) {
        int r = i * 4 + r4;
        tile[r][c] = W[(size_t)(k0 + r) * N + n0 + c];
    }
    __syncthreads();
#pragma unroll
    for (int i = 0; i < 16; ++i) {
        int r = i * 4 + r4;
        int s = n0 + r;
        int d;
        if (PERM) {
            int a = (s < 1024);
            int s2 = a ? s : s - 1024;
            d = ((s2 >> 7) << 8) + (a ? 0 : 128) + (s2 & 127);
        } else {
            d = s;
        }
        Wt[(size_t)d * K + k0 + c] = f2b(tile[c][r]);
    }
}

// ---------------- norm: alpha*(x-mu)/(std_ddof1+eps)+bias -> bf16 --------
__global__ __launch_bounds__(256) void norm_k(const float* __restrict__ x,
                                              const float* __restrict__ al,
                                              const float* __restrict__ be,
                                              ushort_t* __restrict__ out) {
    int row = blockIdx.x;
    const float4* xr = (const float4*)(x + (size_t)row * 1024);
    float4 v = xr[threadIdx.x];
    float s = v.x + v.y + v.z + v.w;
    float q = v.x * v.x + v.y * v.y + v.z * v.z + v.w * v.w;
#pragma unroll
    for (int o = 32; o > 0; o >>= 1) {
        s += __shfl_down(s, o);
        q += __shfl_down(q, o);
    }
    __shared__ float ss[4], qq[4];
    int lane = threadIdx.x & 63, wv = threadIdx.x >> 6;
    if (lane == 0) { ss[wv] = s; qq[wv] = q; }
    __syncthreads();
    s = ss[0] + ss[1] + ss[2] + ss[3];
    q = qq[0] + qq[1] + qq[2] + qq[3];
    float mu = s * (1.f / 1024.f);
    float var = (q - 1024.f * mu * mu) * (1.f / 1023.f);
    var = fmaxf(var, 0.f);
    float inv = 1.f / (sqrtf(var) + 1e-6f);
    float4 a4 = ((const float4*)al)[threadIdx.x];
    float4 b4 = ((const float4*)be)[threadIdx.x];
    ushort4 o4;
    o4.x = f2b(a4.x * (v.x - mu) * inv + b4.x);
    o4.y = f2b(a4.y * (v.y - mu) * inv + b4.y);
    o4.z = f2b(a4.z * (v.z - mu) * inv + b4.z);
    o4.w = f2b(a4.w * (v.w - mu) * inv + b4.w);
    ((ushort4*)(out + (size_t)row * 1024))[threadIdx.x] = o4;
}

// ---------------- depthwise lightconv K=3, softmax weights ----------------
__global__ __launch_bounds__(256) void conv_k(const ushort_t* __restrict__ g,
                                              const float* __restrict__ cw,
                                              ushort_t* __restrict__ out) {
    int i = blockIdx.x * 256 + threadIdx.x;
    int row = i >> 7;
    int cc = (i & 127) << 3;
    int s = row & 1023;
    int head = cc >> 6;
    float w0 = cw[head * 3 + 0], w1 = cw[head * 3 + 1], w2 = cw[head * 3 + 2];
    float mx = fmaxf(w0, fmaxf(w1, w2));
    float e0 = __expf(w0 - mx), e1 = __expf(w1 - mx), e2 = __expf(w2 - mx);
    float inv = 1.f / (e0 + e1 + e2);
    w0 = e0 * inv; w1 = e1 * inv; w2 = e2 * inv;
    size_t base = (size_t)row * 1024 + cc;
    s8v z = {0, 0, 0, 0, 0, 0, 0, 0};
    s8v vm = (s > 0)    ? *(const s8v*)(g + base - 1024) : z;
    s8v v0 = *(const s8v*)(g + base);
    s8v vp = (s < 1023) ? *(const s8v*)(g + base + 1024) : z;
    s8v ov;
#pragma unroll
    for (int j = 0; j < 8; ++j) {
        float r = w0 * b2f((ushort_t)vm[j]) + w1 * b2f((ushort_t)v0[j]) +
                  w2 * b2f((ushort_t)vp[j]);
        ov[j] = (short)f2b(r);
    }
    *(s8v*)(out + base) = ov;
}

// ---------------- bf16 GEMM, 256x256, BK=32, RING-2 (64KB -> 2 blk/CU) ---
// r5-proven 2-segment loop; ring-2 so LDS = 64KB => 2 blocks/CU (VGPR ~120
// allows 16 waves/CU). Distance-1 prefetch => ONE vmcnt(0)+barrier per
// tile; exposed drain (~300-500cyc) is covered by the co-resident block
// (m97/m114 inter-block slip). Proven 0-conflict slot-XOR swizzle.
// EPI: 2 = bf16 relu(+bias); 3 = GLU (PERM'd W_l1): g=a*sig(b)*mask.
// Epilogue two-pass (64KB LDS): pass h covers acc m=4h..4h+3.
template <int EPI>
__global__ __launch_bounds__(512, 1) void gemm2r_k(
    const ushort_t* __restrict__ A, const ushort_t* __restrict__ Bt,
    const float* __restrict__ bias, const int* __restrict__ maskp,
    ushort_t* outb, int N, int K) {
    __shared__ char smem[65536] __attribute__((aligned(128)));
    const int NBN = N >> 8;
    const int per = gridDim.x >> 3;
    const int tt = (blockIdx.x & 7) * per + (blockIdx.x >> 3);  // XCD strips
    const int gw = NBN << 3;            // GROUP_M = 8
    const int g = tt / gw;
    const int rem = tt - g * gw;
    const int bm = (g << 3) + (rem & 7);
    const int bn = rem >> 3;

    const int t = threadIdx.x;
    const int l = t & 63, w = t >> 6;
    const int wm = w >> 2, wn = w & 3;
    const int lr = l & 15, lk = l >> 4;

    const int swzel = (((t & 3) ^ ((t >> 3) & 3)) << 3);
    const int r0 = t >> 2;
    const ushort_t* pA0 = A + (size_t)(bm * 256 + r0) * K + swzel;
    const ushort_t* pA1 = pA0 + (size_t)128 * K;
    const ushort_t* pB0 = Bt + (size_t)(bn * 256 + r0) * K + swzel;
    const ushort_t* pB1 = pB0 + (size_t)128 * K;

    const int fswz = ((lk ^ ((lr >> 1) & 3)) << 4);
    int aoff[8], boff[4];
#pragma unroll
    for (int m = 0; m < 8; ++m)
        aoff[m] = (wm * 128 + m * 16 + lr) * 64 + fswz;
#pragma unroll
    for (int n = 0; n < 4; ++n)
        boff[n] = 16384 + (wn * 64 + n * 16 + lr) * 64 + fswz;

    f4v acc[8][4];
#pragma unroll
    for (int m = 0; m < 8; ++m)
#pragma unroll
        for (int n = 0; n < 4; ++n) acc[m][n] = f4v{0.f, 0.f, 0.f, 0.f};

    const int NK = K >> 5;

    // ---- prologue: stage tile 0 -> buf0 ----
    glds16(pA0, smem + t * 16);
    glds16(pA1, smem + 8192 + t * 16);
    glds16(pB0, smem + 16384 + t * 16);
    glds16(pB1, smem + 24576 + t * 16);
    asm volatile("s_waitcnt vmcnt(0)");
    __builtin_amdgcn_s_barrier();
    __builtin_amdgcn_sched_barrier(0);

    s8v aL0[4], bF0[4], aL1[4], bF1[4], aH[4];
#pragma unroll
    for (int m = 0; m < 4; ++m) aL0[m] = *(const s8v*)(smem + aoff[m]);
#pragma unroll
    for (int n = 0; n < 4; ++n) bF0[n] = *(const s8v*)(smem + boff[n]);

#define KSTEP2(I, CAL, CBF, NAL, NBF)                                          \
    {                                                                          \
        const int i_ = (I);                                                    \
        const char* cb_ = smem + (size_t)(i_ & 1) * 32768;                     \
        const char* nb_ = smem + (size_t)((i_ + 1) & 1) * 32768;               \
        int st_ = i_ + 1; if (st_ >= NK) st_ = NK - 1;                         \
        char* sd_ = smem + (size_t)((i_ + 1) & 1) * 32768 + t * 16;            \
        const int ko_ = st_ * 32;                                              \
        /* seg1: aH reads | stage tile i+1 | MFMA low */                       \
        _Pragma("unroll")                                                      \
        for (int m = 0; m < 4; ++m) aH[m] = *(const s8v*)(cb_ + aoff[4 + m]);  \
        glds16(pA0 + ko_, sd_);                                                \
        glds16(pA1 + ko_, sd_ + 8192);                                         \
        glds16(pB0 + ko_, sd_ + 16384);                                        \
        glds16(pB1 + ko_, sd_ + 24576);                                        \
        __builtin_amdgcn_s_setprio(1);                                         \
        _Pragma("unroll")                                                      \
        for (int m = 0; m < 4; ++m)                                            \
            _Pragma("unroll")                                                  \
            for (int n = 0; n < 4; ++n)                                        \
                acc[m][n] = __builtin_amdgcn_mfma_f32_16x16x32_bf16(           \
                    CAL[m], CBF[n], acc[m][n], 0, 0, 0);                       \
        __builtin_amdgcn_s_setprio(0);                                         \
        __builtin_amdgcn_sched_barrier(0);                                     \
        asm volatile("s_waitcnt vmcnt(0)");   /* tile i+1 landed */            \
        __builtin_amdgcn_s_barrier();                                          \
        __builtin_amdgcn_sched_barrier(0);                                     \
        /* seg2: next-tile aL/bF reads | MFMA high */                          \
        _Pragma("unroll")                                                      \
        for (int m = 0; m < 4; ++m) NAL[m] = *(const s8v*)(nb_ + aoff[m]);     \
        _Pragma("unroll")                                                      \
        for (int n = 0; n < 4; ++n) NBF[n] = *(const s8v*)(nb_ + boff[n]);     \
        __builtin_amdgcn_s_setprio(1);                                         \
        _Pragma("unroll")                                                      \
        for (int m = 0; m < 4; ++m)                                            \
            _Pragma("unroll")                                                  \
            for (int n = 0; n < 4; ++n)                                        \
                acc[4 + m][n] = __builtin_amdgcn_mfma_f32_16x16x32_bf16(       \
                    aH[m], CBF[n], acc[4 + m][n], 0, 0, 0);                    \
        __builtin_amdgcn_s_setprio(0);                                         \
    }

    for (int ii = 0; ii < NK; ii += 2) {
        KSTEP2(ii, aL0, bF0, aL1, bF1);
        KSTEP2(ii + 1, aL1, bF1, aL0, bF0);
    }
#undef KSTEP2

    // ---------------- two-pass LDS epilogue (64KB) ----------------
    // C/D: col = lane&15, row = (lane>>4)*4 + reg.
    // Pass h covers acc m = 4h..4h+3; compressed LDS row = wm*64 + m4*16 +
    // lk*4 + r in [0,128); global row = bm*256 + (row>>6)*128 + 64h + (row&63).
    __builtin_amdgcn_s_barrier();
    float bb4[4];
#pragma unroll
    for (int n = 0; n < 4; ++n) {
        int d = bn * 256 + wn * 64 + n * 16 + lr;
        int src = d;
        if (EPI == 3)
            src = ((d >> 8) << 7) + (d & 127) + (((d >> 7) & 1) << 10);
        bb4[n] = bias[src];
    }
#pragma unroll
    for (int h = 0; h < 2; ++h) {
#pragma unroll
        for (int m4 = 0; m4 < 4; ++m4)
#pragma unroll
            for (int n = 0; n < 4; ++n)
#pragma unroll
                for (int r = 0; r < 4; ++r) {
                    int row = wm * 64 + m4 * 16 + lk * 4 + r;
                    int colb = ((wn * 64 + n * 16 + lr) * 2) ^ ((row & 3) << 4);
                    float v = acc[h * 4 + m4][n][r] + bb4[n];
                    if (EPI == 2) v = fmaxf(v, 0.f);
                    *(ushort_t*)(smem + row * 512 + colb) = f2b(v);
                }
        __builtin_amdgcn_s_barrier();
        if (EPI == 3) {
            // GLU readout: a-chunk [0,256B) of each row, b-chunk +256B
#pragma unroll
            for (int s = 0; s < 4; ++s) {
                int row = s * 32 + (t >> 4);
                int abyt = row * 512 + (((t & 15) * 16) ^ ((row & 3) << 4));
                s8v av = *(const s8v*)(smem + abyt);
                s8v bv = *(const s8v*)(smem + abyt + 256);
                int grow = bm * 256 + ((row >> 6) << 7) + 64 * h + (row & 63);
                float mval = (maskp[grow] == 0) ? 0.f : 1.f;
                s8v ov;
#pragma unroll
                for (int j = 0; j < 8; ++j) {
                    float a = b2f((ushort_t)av[j]);
                    float xx = b2f((ushort_t)bv[j]);
                    ov[j] = (short)f2b(a * mval / (1.f + __expf(-xx)));
                }
                *(s8v*)(outb + (size_t)grow * (N >> 1) + bn * 128 +
                        (t & 15) * 8) = ov;
            }
        } else {
#pragma unroll
            for (int s = 0; s < 8; ++s) {
                int row = s * 16 + (t >> 5);
                int byt = row * 512 + (((t & 31) * 16) ^ ((row & 3) << 4));
                int grow = bm * 256 + ((row >> 6) << 7) + 64 * h + (row & 63);
                int gcol = bn * 256 + (t & 31) * 8;
                *(s8v*)(outb + (size_t)grow * N + gcol) =
                    *(const s8v*)(smem + byt);
            }
        }
        __builtin_amdgcn_s_barrier();
    }
}

// ---------------- bf16 GEMM, 256x256, BK=64, 8-PHASE (r13, 1 blk/CU) -----
// Used for gemm2 and gemm4 (grids of 256 wgs = 1/CU regardless of LDS).
template <int EPI>
__global__ __launch_bounds__(512, 1) void gemm8p_k(
    const ushort_t* __restrict__ A, const ushort_t* __restrict__ Bt,
    const float* __restrict__ bias, const float* res, float* outf,
    ushort_t* outb, int N, int K) {
    __shared__ char smem[131072] __attribute__((aligned(128)));
    const int NBN = N >> 8;
    const int per = gridDim.x >> 3;
    const int tt = (blockIdx.x & 7) * per + (blockIdx.x >> 3);  // XCD strips
    const int gw = NBN << 3;            // GROUP_M = 8
    const int g = tt / gw;
    const int rem = tt - g * gw;
    const int bm = (g << 3) + (rem & 7);
    const int bn = rem >> 3;

    const int t = threadIdx.x;
    const int l = t & 63, w = t >> 6;
    const int wm = w >> 2, wn = w & 3;
    const int lr = l & 15, lk = l >> 4;
    const int t16 = t * 16;

    const int srcsl = (((t & 7) ^ ((t >> 3) & 7)) << 3);
    const int rs = t >> 3;
    const ushort_t* pAL0 = A + (size_t)(bm * 256 + rs) * K + srcsl;
    const ushort_t* pAL1 = pAL0 + (size_t)64 * K;
    const ushort_t* pAH0 = pAL0 + (size_t)128 * K;
    const ushort_t* pAH1 = pAL0 + (size_t)192 * K;
    const ushort_t* pBL0 = Bt + (size_t)(bn * 256 + rs) * K + srcsl;
    const ushort_t* pBL1 = pBL0 + (size_t)64 * K;
    const ushort_t* pBH0 = pBL0 + (size_t)128 * K;
    const ushort_t* pBH1 = pBL0 + (size_t)192 * K;

    const int rowA = (wm * 16 + lr) * 128;
    const int rowB = (wn * 16 + lr) * 128;
    int xk[2];
#pragma unroll
    for (int ks = 0; ks < 2; ++ks)
        xk[ks] = (((ks * 4 + lk) ^ (lr & 7)) << 4);

    f4v acc[8][4];
#pragma unroll
    for (int m = 0; m < 8; ++m)
#pragma unroll
        for (int n = 0; n < 4; ++n) acc[m][n] = f4v{0.f, 0.f, 0.f, 0.f};

    const int NT = K >> 6;

#pragma unroll
    for (int p = 0; p < 2; ++p) {
        char* b = smem + p * 65536 + t16;
        const int ko = p * 64;
        glds16(pAL0 + ko, b);
        glds16(pAL1 + ko, b + 8192);
        glds16(pBL0 + ko, b + 32768);
        glds16(pBL1 + ko, b + 40960);
        glds16(pBH0 + ko, b + 49152);
        glds16(pBH1 + ko, b + 57344);
        glds16(pAH0 + ko, b + 16384);
        glds16(pAH1 + ko, b + 24576);
    }
    asm volatile("s_waitcnt vmcnt(8)");
    __builtin_amdgcn_s_barrier();

    s8v aR[4][2], bR[4][2];

#define MFMAQ(MB, NB)                                                          \
    _Pragma("unroll")                                                          \
    for (int ks = 0; ks < 2; ++ks)                                             \
        _Pragma("unroll")                                                      \
        for (int m = 0; m < 4; ++m)                                            \
            _Pragma("unroll")                                                  \
            for (int n = 0; n < 2; ++n)                                        \
                acc[(MB) + m][(NB) + n] =                                      \
                    __builtin_amdgcn_mfma_f32_16x16x32_bf16(                   \
                        aR[m][ks], bR[(NB) + n][ks],                           \
                        acc[(MB) + m][(NB) + n], 0, 0, 0);

#define KT(TI)                                                                 \
    {                                                                          \
        const int ti_ = (TI);                                                  \
        const char* cb_ = smem + (size_t)(ti_ & 1) * 65536;                    \
        char* sb_ = smem + (size_t)(ti_ & 1) * 65536;                          \
        int st_ = ti_ + 2;                                                     \
        if (st_ >= NT) st_ = NT - 2 + (ti_ & 1);                               \
        const int ko_ = st_ * 64;                                              \
        /* ---- P1 ---- */                                                     \
        _Pragma("unroll")                                                      \
        for (int m = 0; m < 4; ++m)                                            \
            _Pragma("unroll")                                                  \
            for (int ks = 0; ks < 2; ++ks)                                     \
                aR[m][ks] = *(const s8v*)(cb_ + m * 4096 + rowA + xk[ks]);     \
        _Pragma("unroll")                                                      \
        for (int n = 0; n < 2; ++n)                                            \
            _Pragma("unroll")                                                  \
            for (int ks = 0; ks < 2; ++ks)                                     \
                bR[n][ks] =                                                    \
                    *(const s8v*)(cb_ + 32768 + n * 8192 + rowB + xk[ks]);     \
        asm volatile("s_waitcnt lgkmcnt(8)");                                  \
        __builtin_amdgcn_s_barrier();                                          \
        asm volatile("s_waitcnt lgkmcnt(0)");                                  \
        __builtin_amdgcn_s_setprio(1);                                         \
        MFMAQ(0, 0)                                                            \
        __builtin_amdgcn_s_setprio(0);                                         \
        __builtin_amdgcn_s_barrier();                                          \
        /* ---- P2 ---- */                                                     \
        _Pragma("unroll")                                                      \
        for (int n = 0; n < 2; ++n)                                            \
            _Pragma("unroll")                                                  \
            for (int ks = 0; ks < 2; ++ks)                                     \
                bR[2 + n][ks] =                                                \
                    *(const s8v*)(cb_ + 49152 + n * 8192 + rowB + xk[ks]);     \
        glds16(pAL0 + ko_, sb_ + t16);                                         \
        glds16(pAL1 + ko_, sb_ + 8192 + t16);                                  \
        __builtin_amdgcn_s_barrier();                                          \
        asm volatile("s_waitcnt lgkmcnt(0)");                                  \
        __builtin_amdgcn_s_setprio(1);                                         \
        MFMAQ(0, 2)                                                            \
        __builtin_amdgcn_s_setprio(0);                                         \
        __builtin_amdgcn_s_barrier();                                          \
        /* ---- P3 ---- */                                                     \
        _Pragma("unroll")                                                      \
        for (int m = 0; m < 4; ++m)                                            \
            _Pragma("unroll")                                                  \
            for (int ks = 0; ks < 2; ++ks)                                     \
                aR[m][ks] =                                                    \
                    *(const s8v*)(cb_ + 16384 + m * 4096 + rowA + xk[ks]);     \
        glds16(pBL0 + ko_, sb_ + 32768 + t16);                                 \
        glds16(pBL1 + ko_, sb_ + 40960 + t16);                                 \
        __builtin_amdgcn_s_barrier();                                          \
        asm volatile("s_waitcnt lgkmcnt(0)");                                  \
        __builtin_amdgcn_s_setprio(1);                                         \
        MFMAQ(4, 0)                                                            \
        __builtin_amdgcn_s_setprio(0);                                         \
        __builtin_amdgcn_s_barrier();                                          \
        /* ---- P4 ---- */                                                     \
        glds16(pBH0 + ko_, sb_ + 49152 + t16);                                 \
        glds16(pBH1 + ko_, sb_ + 57344 + t16);                                 \
        glds16(pAH0 + ko_, sb_ + 16384 + t16);                                 \
        glds16(pAH1 + ko_, sb_ + 24576 + t16);                                 \
        asm volatile("s_waitcnt vmcnt(6)");                                    \
        __builtin_amdgcn_s_barrier();                                          \
        __builtin_amdgcn_s_setprio(1);                                         \
        MFMAQ(4, 2)                                                            \
        __builtin_amdgcn_s_setprio(0);                                         \
        __builtin_amdgcn_s_barrier();                                          \
    }

    for (int j = 0; j < NT; j += 2) {
        KT(j);
        KT(j + 1);
    }
#undef KT
#undef MFMAQ

    if (EPI == 1) {
#pragma unroll
        for (int n = 0; n < 4; ++n) {
            int gcol = bn * 256 + n * 64 + wn * 16 + lr;
            float bb = bias[gcol];
#pragma unroll
            for (int m = 0; m < 8; ++m) {
#pragma unroll
                for (int r = 0; r < 4; ++r) {
                    int grow = bm * 256 + m * 32 + wm * 16 + lk * 4 + r;
                    size_t oi = (size_t)grow * N + gcol;
                    outf[oi] = acc[m][n][r] + bb + res[oi];
                }
            }
        }
    } else {
        asm volatile("s_waitcnt vmcnt(0)" ::: "memory");
        __builtin_amdgcn_s_barrier();
        float bb4[4];
#pragma unroll
        for (int n = 0; n < 4; ++n)
            bb4[n] = bias[bn * 256 + n * 64 + wn * 16 + lr];
#pragma unroll
        for (int m = 0; m < 8; ++m)
#pragma unroll
            for (int n = 0; n < 4; ++n)
#pragma unroll
                for (int r = 0; r < 4; ++r) {
                    int row = m * 32 + wm * 16 + lk * 4 + r;
                    int colb =
                        ((n * 64 + wn * 16 + lr) * 2) ^ ((row & 3) << 4);
                    *(ushort_t*)(smem + row * 512 + colb) =
                        f2b(fmaxf(acc[m][n][r] + bb4[n], 0.f));
                }
        __builtin_amdgcn_s_barrier();
#pragma unroll
        for (int s = 0; s < 16; ++s) {
            int row = s * 16 + (t >> 5);
            int byt = row * 512 + (((t & 31) * 16) ^ ((row & 3) << 4));
            int grow = bm * 256 + row;
            int gcol = bn * 256 + (t & 31) * 8;
            *(s8v*)(outb + (size_t)grow * N + gcol) = *(const s8v*)(smem + byt);
        }
    }
}

extern "C" void kernel_launch(void* const* d_in, const int* in_sizes, int n_in,
                              void* d_out, int out_size, void* d_ws, size_t ws_size,
                              hipStream_t stream) {
    const float* x      = (const float*)d_in[0];
    const int*   mask   = (const int*)d_in[1];
    const float* alpha1 = (const float*)d_in[2];
    const float* bias1  = (const float*)d_in[3];
    const float* alpha2 = (const float*)d_in[4];
    const float* bias2  = (const float*)d_in[5];
    const float* W_l1   = (const float*)d_in[6];
    const float* b_l1   = (const float*)d_in[7];
    const float* conv_w = (const float*)d_in[8];
    const float* W_l2   = (const float*)d_in[9];
    const float* b_l2   = (const float*)d_in[10];
    const float* W_ff1  = (const float*)d_in[11];
    const float* b_ff1  = (const float*)d_in[12];
    const float* W_ff2  = (const float*)d_in[13];
    const float* b_ff2  = (const float*)d_in[14];
    float* out = (float*)d_out;

    char* ws = (char*)d_ws;
    size_t off = 0;
    auto alloc = [&](size_t b) {
        char* p = ws + off;
        off += (b + 255) & ~(size_t)255;
        return p;
    };
    ushort_t* Wl1t  = (ushort_t*)alloc(2048ull * 1024 * 2);
    ushort_t* Wl2t  = (ushort_t*)alloc(1024ull * 1024 * 2);
    ushort_t* Wff1t = (ushort_t*)alloc(4096ull * 1024 * 2);
    ushort_t* Wff2t = (ushort_t*)alloc(1024ull * 4096 * 2);
    char* regA = alloc(134217728ull);             // g / f1
    ushort_t* B1 = (ushort_t*)alloc(33554432ull); // h1 / h2
    ushort_t* C1 = (ushort_t*)alloc(33554432ull); // conv-out
    ushort_t* G1 = (ushort_t*)regA;               // GLU output (dead before f1)
    ushort_t* f1 = (ushort_t*)regA;

    const int R = 16384;  // B*S rows

    trans_k<1><<<dim3(16, 32), 256, 0, stream>>>(W_l1, Wl1t, 1024, 2048);
    trans_k<0><<<dim3(16, 16), 256, 0, stream>>>(W_l2, Wl2t, 1024, 1024);
    trans_k<0><<<dim3(16, 64), 256, 0, stream>>>(W_ff1, Wff1t, 1024, 4096);
    trans_k<0><<<dim3(64, 16), 256, 0, stream>>>(W_ff2, Wff2t, 4096, 1024);

    // sublayer 1: norm -> GEMM(D,2D)+bias+GLU+mask (ring-2) -> conv -> GEMM+res
    norm_k<<<R, 256, 0, stream>>>(x, alpha1, bias1, B1);
    gemm2r_k<3><<<64 * 8, 512, 0, stream>>>(B1, Wl1t, b_l1, mask, G1, 2048,
                                            1024);
    conv_k<<<8192, 256, 0, stream>>>(G1, conv_w, C1);
    gemm8p_k<1><<<64 * 4, 512, 0, stream>>>(C1, Wl2t, b_l2, x, out, nullptr,
                                            1024, 1024);

    // sublayer 2: norm -> GEMM(D,DFF)+bias+relu (ring-2) -> GEMM(DFF,D)+res
    norm_k<<<R, 256, 0, stream>>>(out, alpha2, bias2, B1);
    gemm2r_k<2><<<64 * 16, 512, 0, stream>>>(B1, Wff1t, b_ff1, nullptr, f1,
                                             4096, 1024);
    gemm8p_k<1><<<64 * 4, 512, 0, stream>>>(f1, Wff2t, b_ff2, out, out,
                                            nullptr, 1024, 4096);
}

// Round 15
// 504.247 us; speedup vs baseline: 1.0689x; 1.0689x over previous
//
#include <hip/hip_runtime.h>

typedef unsigned short ushort_t;
typedef __attribute__((ext_vector_type(8))) short s8v;
typedef __attribute__((ext_vector_type(4))) float f4v;

__device__ __forceinline__ float b2f(ushort_t h) {
    union { unsigned u; float f; } c; c.u = ((unsigned)h) << 16; return c.f;
}
__device__ __forceinline__ ushort_t f2b(float f) {
    union { float f; unsigned u; } c; c.f = f;
    unsigned u = c.u;
    return (ushort_t)((u + 0x7fffu + ((u >> 16) & 1u)) >> 16);
}

__device__ __forceinline__ void glds16(const void* g, void* l) {
    __builtin_amdgcn_global_load_lds(
        (const __attribute__((address_space(1))) void*)g,
        (__attribute__((address_space(3))) void*)l, 16, 0, 0);
}

// ---------------- weight transpose f32 [K,N] -> bf16 [N,K] ----------------
template <int PERM>
__global__ __launch_bounds__(256) void trans_k(const float* __restrict__ W,
                                               ushort_t* __restrict__ Wt,
                                               int K, int N) {
    __shared__ float tile[64][65];
    int k0 = blockIdx.x * 64, n0 = blockIdx.y * 64;
    int t = threadIdx.x;
    int c = t & 63, r4 = t >> 6;
#pragma unroll
    for (int i = 0; i < 16; ++i) {
        int r = i * 4 + r4;
        tile[r][c] = W[(size_t)(k0 + r) * N + n0 + c];
    }
    __syncthreads();
#pragma unroll
    for (int i = 0; i < 16; ++i) {
        int r = i * 4 + r4;
        int s = n0 + r;
        int d;
        if (PERM) {
            int a = (s < 1024);
            int s2 = a ? s : s - 1024;
            d = ((s2 >> 7) << 8) + (a ? 0 : 128) + (s2 & 127);
        } else {
            d = s;
        }
        Wt[(size_t)d * K + k0 + c] = f2b(tile[c][r]);
    }
}

// ---------------- norm: alpha*(x-mu)/(std_ddof1+eps)+bias -> bf16 --------
__global__ __launch_bounds__(256) void norm_k(const float* __restrict__ x,
                                              const float* __restrict__ al,
                                              const float* __restrict__ be,
                                              ushort_t* __restrict__ out) {
    int row = blockIdx.x;
    const float4* xr = (const float4*)(x + (size_t)row * 1024);
    float4 v = xr[threadIdx.x];
    float s = v.x + v.y + v.z + v.w;
    float q = v.x * v.x + v.y * v.y + v.z * v.z + v.w * v.w;
#pragma unroll
    for (int o = 32; o > 0; o >>= 1) {
        s += __shfl_down(s, o);
        q += __shfl_down(q, o);
    }
    __shared__ float ss[4], qq[4];
    int lane = threadIdx.x & 63, wv = threadIdx.x >> 6;
    if (lane == 0) { ss[wv] = s; qq[wv] = q; }
    __syncthreads();
    s = ss[0] + ss[1] + ss[2] + ss[3];
    q = qq[0] + qq[1] + qq[2] + qq[3];
    float mu = s * (1.f / 1024.f);
    float var = (q - 1024.f * mu * mu) * (1.f / 1023.f);
    var = fmaxf(var, 0.f);
    float inv = 1.f / (sqrtf(var) + 1e-6f);
    float4 a4 = ((const float4*)al)[threadIdx.x];
    float4 b4 = ((const float4*)be)[threadIdx.x];
    ushort4 o4;
    o4.x = f2b(a4.x * (v.x - mu) * inv + b4.x);
    o4.y = f2b(a4.y * (v.y - mu) * inv + b4.y);
    o4.z = f2b(a4.z * (v.z - mu) * inv + b4.z);
    o4.w = f2b(a4.w * (v.w - mu) * inv + b4.w);
    ((ushort4*)(out + (size_t)row * 1024))[threadIdx.x] = o4;
}

// ---------------- depthwise lightconv K=3, softmax weights ----------------
__global__ __launch_bounds__(256) void conv_k(const ushort_t* __restrict__ g,
                                              const float* __restrict__ cw,
                                              ushort_t* __restrict__ out) {
    int i = blockIdx.x * 256 + threadIdx.x;
    int row = i >> 7;
    int cc = (i & 127) << 3;
    int s = row & 1023;
    int head = cc >> 6;
    float w0 = cw[head * 3 + 0], w1 = cw[head * 3 + 1], w2 = cw[head * 3 + 2];
    float mx = fmaxf(w0, fmaxf(w1, w2));
    float e0 = __expf(w0 - mx), e1 = __expf(w1 - mx), e2 = __expf(w2 - mx);
    float inv = 1.f / (e0 + e1 + e2);
    w0 = e0 * inv; w1 = e1 * inv; w2 = e2 * inv;
    size_t base = (size_t)row * 1024 + cc;
    s8v z = {0, 0, 0, 0, 0, 0, 0, 0};
    s8v vm = (s > 0)    ? *(const s8v*)(g + base - 1024) : z;
    s8v v0 = *(const s8v*)(g + base);
    s8v vp = (s < 1023) ? *(const s8v*)(g + base + 1024) : z;
    s8v ov;
#pragma unroll
    for (int j = 0; j < 8; ++j) {
        float r = w0 * b2f((ushort_t)vm[j]) + w1 * b2f((ushort_t)v0[j]) +
                  w2 * b2f((ushort_t)vp[j]);
        ov[j] = (short)f2b(r);
    }
    *(s8v*)(out + base) = ov;
}

// ---------------- bf16 GEMM, 256x256 tile, 8 waves (r10/r13 gemm1) -------
// EPI 3 = GLU epilogue (PERM'd W_l1): g = a*sigmoid(b)*mask.
template <int EPI>
__global__ __launch_bounds__(512, 1) void gemm_k(const ushort_t* __restrict__ A,
                                                 const ushort_t* __restrict__ Bt,
                                                 const float* __restrict__ bias,
                                                 const int* __restrict__ maskp,
                                                 const float* res, float* outf,
                                                 ushort_t* outb, int N, int K) {
    __shared__ char smem[131072] __attribute__((aligned(128)));
    const int NBN = N >> 8;
    const int per = gridDim.x >> 3;
    const int tt = (blockIdx.x & 7) * per + (blockIdx.x >> 3);  // XCD strips
    const int gw = NBN << 3;            // GROUP_M = 8
    const int g = tt / gw;
    const int rem = tt - g * gw;
    const int bm = (g << 3) + (rem & 7);
    const int bn = rem >> 3;

    const int t = threadIdx.x;
    const int l = t & 63, w = t >> 6;
    const int wm = w >> 2, wn = w & 3;
    const int lr = l & 15, lk = l >> 4;

    const int swzel = (((t & 3) ^ ((t >> 3) & 3)) << 3);
    const int r0 = t >> 2;
    const ushort_t* pA0 = A + (size_t)(bm * 256 + r0) * K + swzel;
    const ushort_t* pA1 = pA0 + (size_t)128 * K;
    const ushort_t* pB0 = Bt + (size_t)(bn * 256 + r0) * K + swzel;
    const ushort_t* pB1 = pB0 + (size_t)128 * K;

    const int fswz = ((lk ^ ((lr >> 1) & 3)) << 4);
    int aoff[8], boff[4];
#pragma unroll
    for (int m = 0; m < 8; ++m)
        aoff[m] = (wm * 128 + m * 16 + lr) * 64 + fswz;
#pragma unroll
    for (int n = 0; n < 4; ++n)
        boff[n] = 16384 + (wn * 64 + n * 16 + lr) * 64 + fswz;

    f4v acc[8][4];
#pragma unroll
    for (int m = 0; m < 8; ++m)
#pragma unroll
        for (int n = 0; n < 4; ++n) acc[m][n] = f4v{0.f, 0.f, 0.f, 0.f};

    const int NK = K >> 5;

#pragma unroll
    for (int p = 0; p < 3; ++p) {
        char* d = smem + p * 32768 + t * 16;
        glds16(pA0 + p * 32, d);
        glds16(pA1 + p * 32, d + 8192);
        glds16(pB0 + p * 32, d + 16384);
        glds16(pB1 + p * 32, d + 24576);
    }
    asm volatile("s_waitcnt vmcnt(8)");
    __builtin_amdgcn_s_barrier();
    __builtin_amdgcn_sched_barrier(0);

    s8v aL0[4], bF0[4], aL1[4], bF1[4], aH[4];
#pragma unroll
    for (int m = 0; m < 4; ++m) aL0[m] = *(const s8v*)(smem + aoff[m]);
#pragma unroll
    for (int n = 0; n < 4; ++n) bF0[n] = *(const s8v*)(smem + boff[n]);

#define KSTEP(I, CAL, CBF, NAL, NBF)                                           \
    {                                                                          \
        const int i_ = (I);                                                    \
        const char* cb_ = smem + (size_t)(i_ & 3) * 32768;                     \
        const char* nb_ = smem + (size_t)((i_ + 1) & 3) * 32768;               \
        int st_ = i_ + 3; if (st_ >= NK) st_ = NK - 1;                         \
        char* sd_ = smem + (size_t)((i_ + 3) & 3) * 32768 + t * 16;            \
        const int ko_ = st_ * 32;                                              \
        _Pragma("unroll")                                                      \
        for (int m = 0; m < 4; ++m) aH[m] = *(const s8v*)(cb_ + aoff[4 + m]);  \
        glds16(pA0 + ko_, sd_);                                                \
        glds16(pA1 + ko_, sd_ + 8192);                                         \
        glds16(pB0 + ko_, sd_ + 16384);                                        \
        glds16(pB1 + ko_, sd_ + 24576);                                        \
        __builtin_amdgcn_s_setprio(1);                                         \
        _Pragma("unroll")                                                      \
        for (int m = 0; m < 4; ++m)                                            \
            _Pragma("unroll")                                                  \
            for (int n = 0; n < 4; ++n)                                        \
                acc[m][n] = __builtin_amdgcn_mfma_f32_16x16x32_bf16(           \
                    CAL[m], CBF[n], acc[m][n], 0, 0, 0);                       \
        __builtin_amdgcn_s_setprio(0);                                         \
        __builtin_amdgcn_sched_barrier(0);                                     \
        asm volatile("s_waitcnt vmcnt(6)");                                    \
        __builtin_amdgcn_s_barrier();                                          \
        __builtin_amdgcn_sched_barrier(0);                                     \
        _Pragma("unroll")                                                      \
        for (int m = 0; m < 4; ++m) NAL[m] = *(const s8v*)(nb_ + aoff[m]);     \
        _Pragma("unroll")                                                      \
        for (int n = 0; n < 4; ++n) NBF[n] = *(const s8v*)(nb_ + boff[n]);     \
        __builtin_amdgcn_s_setprio(1);                                         \
        _Pragma("unroll")                                                      \
        for (int m = 0; m < 4; ++m)                                            \
            _Pragma("unroll")                                                  \
            for (int n = 0; n < 4; ++n)                                        \
                acc[4 + m][n] = __builtin_amdgcn_mfma_f32_16x16x32_bf16(       \
                    aH[m], CBF[n], acc[4 + m][n], 0, 0, 0);                    \
        __builtin_amdgcn_s_setprio(0);                                         \
    }

    for (int ii = 0; ii < NK; ii += 2) {
        KSTEP(ii, aL0, bF0, aL1, bF1);
        KSTEP(ii + 1, aL1, bF1, aL0, bF0);
    }
#undef KSTEP

    asm volatile("s_waitcnt vmcnt(0)" ::: "memory");
    __builtin_amdgcn_s_barrier();
    float bb4[4];
#pragma unroll
    for (int n = 0; n < 4; ++n) {
        int d = bn * 256 + wn * 64 + n * 16 + lr;
        int src = ((d >> 8) << 7) + (d & 127) + (((d >> 7) & 1) << 10);
        bb4[n] = bias[src];
    }
#pragma unroll
    for (int m = 0; m < 8; ++m)
#pragma unroll
        for (int n = 0; n < 4; ++n)
#pragma unroll
            for (int r = 0; r < 4; ++r) {
                int row = wm * 128 + m * 16 + lk * 4 + r;
                int colb = ((wn * 64 + n * 16 + lr) * 2) ^ ((row & 3) << 4);
                *(ushort_t*)(smem + row * 512 + colb) =
                    f2b(acc[m][n][r] + bb4[n]);
            }
    __builtin_amdgcn_s_barrier();
#pragma unroll
    for (int s = 0; s < 8; ++s) {
        int row = s * 32 + (t >> 4);
        int abyt = row * 512 + (((t & 15) * 16) ^ ((row & 3) << 4));
        s8v av = *(const s8v*)(smem + abyt);
        s8v bv = *(const s8v*)(smem + abyt + 256);
        int grow = bm * 256 + row;
        float mval = (maskp[grow] == 0) ? 0.f : 1.f;
        s8v ov;
#pragma unroll
        for (int j = 0; j < 8; ++j) {
            float a = b2f((ushort_t)av[j]);
            float xx = b2f((ushort_t)bv[j]);
            ov[j] = (short)f2b(a * mval / (1.f + __expf(-xx)));
        }
        *(s8v*)(outb + (size_t)grow * (N >> 1) + bn * 128 + (t & 15) * 8) = ov;
    }
}

// ---------------- bf16 GEMM, 256x256, BK=64, SHADOW-READ 4-phase ---------
// Per phase: lgkm(0) -> 16 MFMA -> ds_reads for NEXT quadrant (in the MFMA
// shadow: LDS pipe serves them while other waves MFMA / wait) -> stages ->
// barrier. 4 barriers/K-tile (was 8). Quadrant operand plan (ring-2 64KB
// buffers, regions {A-low,A-high,B-low,B-high} of [128r][128B]):
//   P4(ti-1) end: rd A-low(ti)->A0[12 w/ B-low->B0]  (after vmcnt(8) gate)
//   P1: MFMA(A0,B0 -> m0-3,n0-1); rd B-high->B1; stage A-low,B-low(ti+2)
//   P2: MFMA(A0,B1 -> m0-3,n2-3); rd A-high->A1;  stage B-high(ti+2)
//   P3: MFMA(A1,B0 -> m4-7,n0-1);                 stage A-high(ti+2)
//   P4: MFMA(A1,B1 -> m4-7,n2-3); vmcnt(8); rd A-low/B-low(ti+1)
// Race-audit: each region's stage is issued after the lgkm(0) that retired
// its final reader; cross-tile reads pinned after counted vmcnt(8) (= tile
// ti+1's 8 stages landed, ti+2's 8 stay in flight).
// EPI: 1 = f32 out (+bias+res); 2 = bf16 relu(+bias)
template <int EPI>
__global__ __launch_bounds__(512, 1) void gemmsp_k(
    const ushort_t* __restrict__ A, const ushort_t* __restrict__ Bt,
    const float* __restrict__ bias, const float* res, float* outf,
    ushort_t* outb, int N, int K) {
    __shared__ char smem[131072] __attribute__((aligned(128)));
    const int NBN = N >> 8;
    const int per = gridDim.x >> 3;
    const int tt = (blockIdx.x & 7) * per + (blockIdx.x >> 3);  // XCD strips
    const int gw = NBN << 3;            // GROUP_M = 8
    const int g = tt / gw;
    const int rem = tt - g * gw;
    const int bm = (g << 3) + (rem & 7);
    const int bn = rem >> 3;

    const int t = threadIdx.x;
    const int l = t & 63, w = t >> 6;
    const int wm = w >> 2, wn = w & 3;
    const int lr = l & 15, lk = l >> 4;
    const int t16 = t * 16;

    const int srcsl = (((t & 7) ^ ((t >> 3) & 7)) << 3);
    const int rs = t >> 3;
    const ushort_t* pAL0 = A + (size_t)(bm * 256 + rs) * K + srcsl;
    const ushort_t* pAL1 = pAL0 + (size_t)64 * K;
    const ushort_t* pAH0 = pAL0 + (size_t)128 * K;
    const ushort_t* pAH1 = pAL0 + (size_t)192 * K;
    const ushort_t* pBL0 = Bt + (size_t)(bn * 256 + rs) * K + srcsl;
    const ushort_t* pBL1 = pBL0 + (size_t)64 * K;
    const ushort_t* pBH0 = pBL0 + (size_t)128 * K;
    const ushort_t* pBH1 = pBL0 + (size_t)192 * K;

    const int rowA = (wm * 16 + lr) * 128;
    const int rowB = (wn * 16 + lr) * 128;
    int xk[2];
#pragma unroll
    for (int ks = 0; ks < 2; ++ks)
        xk[ks] = (((ks * 4 + lk) ^ (lr & 7)) << 4);

    f4v acc[8][4];
#pragma unroll
    for (int m = 0; m < 8; ++m)
#pragma unroll
        for (int n = 0; n < 4; ++n) acc[m][n] = f4v{0.f, 0.f, 0.f, 0.f};

    const int NT = K >> 6;  // even, >= 4

    // ---- prologue: tile0 -> buf0, tile1 -> buf1 ----
#pragma unroll
    for (int p = 0; p < 2; ++p) {
        char* b = smem + p * 65536 + t16;
        const int ko = p * 64;
        glds16(pAL0 + ko, b);
        glds16(pAL1 + ko, b + 8192);
        glds16(pBL0 + ko, b + 32768);
        glds16(pBL1 + ko, b + 40960);
        glds16(pBH0 + ko, b + 49152);
        glds16(pBH1 + ko, b + 57344);
        glds16(pAH0 + ko, b + 16384);
        glds16(pAH1 + ko, b + 24576);
    }
    asm volatile("s_waitcnt vmcnt(8)" ::: "memory");  // tile 0 landed
    __builtin_amdgcn_s_barrier();
    __builtin_amdgcn_sched_barrier(0);

    s8v A0[4][2], A1[4][2], B0[2][2], B1[2][2];
    // initial Q1 operands of tile 0
#pragma unroll
    for (int m = 0; m < 4; ++m)
#pragma unroll
        for (int ks = 0; ks < 2; ++ks)
            A0[m][ks] = *(const s8v*)(smem + m * 4096 + rowA + xk[ks]);
#pragma unroll
    for (int n = 0; n < 2; ++n)
#pragma unroll
        for (int ks = 0; ks < 2; ++ks)
            B0[n][ks] = *(const s8v*)(smem + 32768 + n * 8192 + rowB + xk[ks]);

#define MFMAQ(AR, BR, MB, NB)                                                  \
    _Pragma("unroll")                                                          \
    for (int ks = 0; ks < 2; ++ks)                                             \
        _Pragma("unroll")                                                      \
        for (int m = 0; m < 4; ++m)                                            \
            _Pragma("unroll")                                                  \
            for (int n = 0; n < 2; ++n)                                        \
                acc[(MB) + m][(NB) + n] =                                      \
                    __builtin_amdgcn_mfma_f32_16x16x32_bf16(                   \
                        AR[m][ks], BR[n][ks], acc[(MB) + m][(NB) + n], 0, 0, 0);

    for (int ti = 0; ti < NT; ++ti) {
        const char* cb = smem + (size_t)(ti & 1) * 65536;
        char* sb = smem + (size_t)(ti & 1) * 65536;
        int st = ti + 2;
        if (st >= NT) st = NT - 2 + (ti & 1);       // parity-preserving clamp
        const int ko = st * 64;
        const int nti = (ti + 1 < NT) ? ti + 1 : NT - 1;
        const char* nb = smem + (size_t)(nti & 1) * 65536;

        // ---- P1: MFMA Q1; shadow: rd B-high; stage A-low,B-low(ti+2) ----
        asm volatile("s_waitcnt lgkmcnt(0)" ::: "memory");
        __builtin_amdgcn_sched_barrier(0);
        __builtin_amdgcn_s_setprio(1);
        MFMAQ(A0, B0, 0, 0)
        __builtin_amdgcn_s_setprio(0);
#pragma unroll
        for (int n = 0; n < 2; ++n)
#pragma unroll
            for (int ks = 0; ks < 2; ++ks)
                B1[n][ks] =
                    *(const s8v*)(cb + 49152 + n * 8192 + rowB + xk[ks]);
        glds16(pAL0 + ko, sb + t16);
        glds16(pAL1 + ko, sb + 8192 + t16);
        glds16(pBL0 + ko, sb + 32768 + t16);
        glds16(pBL1 + ko, sb + 40960 + t16);
        __builtin_amdgcn_s_barrier();

        // ---- P2: MFMA Q2; shadow: rd A-high; stage B-high(ti+2) ----
        asm volatile("s_waitcnt lgkmcnt(0)" ::: "memory");
        __builtin_amdgcn_sched_barrier(0);
        __builtin_amdgcn_s_setprio(1);
        MFMAQ(A0, B1, 0, 2)
        __builtin_amdgcn_s_setprio(0);
#pragma unroll
        for (int m = 0; m < 4; ++m)
#pragma unroll
            for (int ks = 0; ks < 2; ++ks)
                A1[m][ks] =
                    *(const s8v*)(cb + 16384 + m * 4096 + rowA + xk[ks]);
        glds16(pBH0 + ko, sb + 49152 + t16);
        glds16(pBH1 + ko, sb + 57344 + t16);
        __builtin_amdgcn_s_barrier();

        // ---- P3: MFMA Q3; stage A-high(ti+2) ----
        asm volatile("s_waitcnt lgkmcnt(0)" ::: "memory");
        __builtin_amdgcn_sched_barrier(0);
        __builtin_amdgcn_s_setprio(1);
        MFMAQ(A1, B0, 4, 0)
        __builtin_amdgcn_s_setprio(0);
        glds16(pAH0 + ko, sb + 16384 + t16);
        glds16(pAH1 + ko, sb + 24576 + t16);
        __builtin_amdgcn_s_barrier();

        // ---- P4: MFMA Q4; vmcnt(8) gate; rd A-low/B-low(ti+1) ----
        __builtin_amdgcn_s_setprio(1);
        MFMAQ(A1, B1, 4, 2)
        __builtin_amdgcn_s_setprio(0);
        asm volatile("s_waitcnt vmcnt(8)" ::: "memory");  // ti+1 landed
        __builtin_amdgcn_sched_barrier(0);
#pragma unroll
        for (int m = 0; m < 4; ++m)
#pragma unroll
            for (int ks = 0; ks < 2; ++ks)
                A0[m][ks] = *(const s8v*)(nb + m * 4096 + rowA + xk[ks]);
#pragma unroll
        for (int n = 0; n < 2; ++n)
#pragma unroll
            for (int ks = 0; ks < 2; ++ks)
                B0[n][ks] =
                    *(const s8v*)(nb + 32768 + n * 8192 + rowB + xk[ks]);
        __builtin_amdgcn_s_barrier();
    }
#undef MFMAQ

    // ---------------- epilogue ----------------
    // C row = m*32 + wm*16 + lk*4 + r; col = n*64 + wn*16 + lr
    if (EPI == 1) {
#pragma unroll
        for (int n = 0; n < 4; ++n) {
            int gcol = bn * 256 + n * 64 + wn * 16 + lr;
            float bb = bias[gcol];
#pragma unroll
            for (int m = 0; m < 8; ++m) {
#pragma unroll
                for (int r = 0; r < 4; ++r) {
                    int grow = bm * 256 + m * 32 + wm * 16 + lk * 4 + r;
                    size_t oi = (size_t)grow * N + gcol;
                    outf[oi] = acc[m][n][r] + bb + res[oi];
                }
            }
        }
    } else {
        asm volatile("s_waitcnt vmcnt(0)" ::: "memory");  // drain tail stages
        __builtin_amdgcn_s_barrier();
        float bb4[4];
#pragma unroll
        for (int n = 0; n < 4; ++n)
            bb4[n] = bias[bn * 256 + n * 64 + wn * 16 + lr];
#pragma unroll
        for (int m = 0; m < 8; ++m)
#pragma unroll
            for (int n = 0; n < 4; ++n)
#pragma unroll
                for (int r = 0; r < 4; ++r) {
                    int row = m * 32 + wm * 16 + lk * 4 + r;
                    int colb =
                        ((n * 64 + wn * 16 + lr) * 2) ^ ((row & 3) << 4);
                    *(ushort_t*)(smem + row * 512 + colb) =
                        f2b(fmaxf(acc[m][n][r] + bb4[n], 0.f));
                }
        __builtin_amdgcn_s_barrier();
#pragma unroll
        for (int s = 0; s < 16; ++s) {
            int row = s * 16 + (t >> 5);
            int byt = row * 512 + (((t & 31) * 16) ^ ((row & 3) << 4));
            int grow = bm * 256 + row;
            int gcol = bn * 256 + (t & 31) * 8;
            *(s8v*)(outb + (size_t)grow * N + gcol) = *(const s8v*)(smem + byt);
        }
    }
}

extern "C" void kernel_launch(void* const* d_in, const int* in_sizes, int n_in,
                              void* d_out, int out_size, void* d_ws, size_t ws_size,
                              hipStream_t stream) {
    const float* x      = (const float*)d_in[0];
    const int*   mask   = (const int*)d_in[1];
    const float* alpha1 = (const float*)d_in[2];
    const float* bias1  = (const float*)d_in[3];
    const float* alpha2 = (const float*)d_in[4];
    const float* bias2  = (const float*)d_in[5];
    const float* W_l1   = (const float*)d_in[6];
    const float* b_l1   = (const float*)d_in[7];
    const float* conv_w = (const float*)d_in[8];
    const float* W_l2   = (const float*)d_in[9];
    const float* b_l2   = (const float*)d_in[10];
    const float* W_ff1  = (const float*)d_in[11];
    const float* b_ff1  = (const float*)d_in[12];
    const float* W_ff2  = (const float*)d_in[13];
    const float* b_ff2  = (const float*)d_in[14];
    float* out = (float*)d_out;

    char* ws = (char*)d_ws;
    size_t off = 0;
    auto alloc = [&](size_t b) {
        char* p = ws + off;
        off += (b + 255) & ~(size_t)255;
        return p;
    };
    ushort_t* Wl1t  = (ushort_t*)alloc(2048ull * 1024 * 2);
    ushort_t* Wl2t  = (ushort_t*)alloc(1024ull * 1024 * 2);
    ushort_t* Wff1t = (ushort_t*)alloc(4096ull * 1024 * 2);
    ushort_t* Wff2t = (ushort_t*)alloc(1024ull * 4096 * 2);
    char* regA = alloc(134217728ull);             // g / f1
    ushort_t* B1 = (ushort_t*)alloc(33554432ull); // h1 / h2
    ushort_t* C1 = (ushort_t*)alloc(33554432ull); // conv-out
    ushort_t* G1 = (ushort_t*)regA;               // GLU output (dead before f1)
    ushort_t* f1 = (ushort_t*)regA;

    const int R = 16384;  // B*S rows

    trans_k<1><<<dim3(16, 32), 256, 0, stream>>>(W_l1, Wl1t, 1024, 2048);
    trans_k<0><<<dim3(16, 16), 256, 0, stream>>>(W_l2, Wl2t, 1024, 1024);
    trans_k<0><<<dim3(16, 64), 256, 0, stream>>>(W_ff1, Wff1t, 1024, 4096);
    trans_k<0><<<dim3(64, 16), 256, 0, stream>>>(W_ff2, Wff2t, 4096, 1024);

    // sublayer 1: norm -> GEMM(D,2D)+bias+GLU+mask (fused) -> conv -> GEMM+res
    norm_k<<<R, 256, 0, stream>>>(x, alpha1, bias1, B1);
    gemm_k<3><<<64 * 8, 512, 0, stream>>>(B1, Wl1t, b_l1, mask, nullptr,
                                          nullptr, G1, 2048, 1024);
    conv_k<<<8192, 256, 0, stream>>>(G1, conv_w, C1);
    gemmsp_k<1><<<64 * 4, 512, 0, stream>>>(C1, Wl2t, b_l2, x, out, nullptr,
                                            1024, 1024);

    // sublayer 2: norm -> GEMM(D,DFF)+bias+relu -> GEMM(DFF,D)+bias+res
    norm_k<<<R, 256, 0, stream>>>(out, alpha2, bias2, B1);
    gemmsp_k<2><<<64 * 16, 512, 0, stream>>>(B1, Wff1t, b_ff1, nullptr,
                                             nullptr, f1, 4096, 1024);
    gemmsp_k<1><<<64 * 4, 512, 0, stream>>>(f1, Wff2t, b_ff2, out, out,
                                            nullptr, 1024, 4096);
}